// Round 15
// baseline (2475.969 us; speedup 1.0000x reference)
//
#include <hip/hip_runtime.h>
#include <hip/hip_cooperative_groups.h>

namespace cg = cooperative_groups;

// LSTM S=512,B=128,IN=256,H=512 — persistent kernel, 128 blocks x 256 thr.
// Round 15: TWO-STREAM INTERLEAVE. Batch rows are independent recurrences;
// each block alternates stream A (16 rows) / stream B (16 rows) of one
// row-pair, same 16 hidden cols (same weight registers). Stream A's LLC
// visibility latency hides under stream B's full compute slot and vice
// versa -> tagged ring reads succeed first try, RT leaves the critical path.
// Per-slot body = round 8/14's PROVEN step (protocol/swizzles/publish).

#define SQ   512
#define BB   128
#define IN_  256
#define HH   512
#define CGN  32
#define RINGHALF (BB * HH)     // dwords
#define RING_OFF 1024          // dwords (4 KB head, unused)

typedef float    f32x4 __attribute__((ext_vector_type(4)));
typedef short    s16x8 __attribute__((ext_vector_type(8)));
typedef unsigned u32x4 __attribute__((ext_vector_type(4)));

struct P {
  const float *x, *h0, *c0;
  const float *W[4], *bW[4], *U[4], *bU[4];   // gate order f,i,o,g
  float* out;        // [SQ][BB][HH] h_seq, then [BB][HH] h, then [BB][HH] c
  unsigned* ring;    // [2][BB][HH] tagged bf16 h (lo16=payload, hi16=tag)
  int mode;          // 0 = ring protocol, 2 = gridsync fallback (no ws)
};

__device__ __forceinline__ unsigned f2b(float f) {
  unsigned u = __float_as_uint(f);
  return (u + 0x7FFFu + ((u >> 16) & 1u)) >> 16;   // RNE f32->bf16
}
__device__ __forceinline__ float sigm(float x) { return 1.f / (1.f + __expf(-x)); }
__device__ __forceinline__ float tanh_(float x) {
  float e = __expf(-2.f * fabsf(x));
  float t = (1.f - e) / (1.f + e);
  return copysignf(t, x);
}
__device__ __forceinline__ u32x4 pack8(f32x4 a, f32x4 b) {
  u32x4 d;
  d.x = f2b(a.x) | (f2b(a.y) << 16);
  d.y = f2b(a.z) | (f2b(a.w) << 16);
  d.z = f2b(b.x) | (f2b(b.y) << 16);
  d.w = f2b(b.z) | (f2b(b.w) << 16);
  return d;
}
// (d0.lo16) | (d1.lo16 << 16) in one v_perm
__device__ __forceinline__ unsigned mergelo(unsigned d0, unsigned d1) {
  return __builtin_amdgcn_perm(d1, d0, 0x05040100u);
}

// 8x dwordx4 from base+{0,256,...,1792}B, ONE waitcnt, LLC-coherent.
#define LOAD8_LLC(c0_,c1_,c2_,c3_,c4_,c5_,c6_,c7_,ptr_)                      \
  asm volatile(                                                              \
    "global_load_dwordx4 %0, %8, off sc0 sc1\n\t"                            \
    "global_load_dwordx4 %1, %8, off offset:256 sc0 sc1\n\t"                 \
    "global_load_dwordx4 %2, %8, off offset:512 sc0 sc1\n\t"                 \
    "global_load_dwordx4 %3, %8, off offset:768 sc0 sc1\n\t"                 \
    "global_load_dwordx4 %4, %8, off offset:1024 sc0 sc1\n\t"                \
    "global_load_dwordx4 %5, %8, off offset:1280 sc0 sc1\n\t"                \
    "global_load_dwordx4 %6, %8, off offset:1536 sc0 sc1\n\t"                \
    "global_load_dwordx4 %7, %8, off offset:1792 sc0 sc1\n\t"                \
    "s_waitcnt vmcnt(0)"                                                     \
    : "=&v"(c0_), "=&v"(c1_), "=&v"(c2_), "=&v"(c3_),                        \
      "=&v"(c4_), "=&v"(c5_), "=&v"(c6_), "=&v"(c7_)                         \
    : "v"(ptr_) : "memory")

// One recurrence slot (stream S): identical to round 8/14's proven step.
template <int S>
__device__ __forceinline__ void slot(const P& p, unsigned* ring, int t,
    int rbS, float& cval,
    f32x4& X0, f32x4& X1, f32x4& X2, f32x4& X3,
    char* HsB, char* XsB, float* gb,
    int row16, int n16, int l16, int lk, int w, int hcb,
    int wswz, int rswz, const s16x8* bfrag, float bias) {
  // ---- A) Xs[S][t&1] <- xreg; issue x(t+1) loads (hide under ring read) ----
  {
    char* xrow = XsB + S * 16384 + (t & 1) * 8192 + row16 * 512;
    *(u32x4*)(xrow + ((n16 * 32)      ^ wswz)) = pack8(X0, X1);
    *(u32x4*)(xrow + ((n16 * 32 + 16) ^ wswz)) = pack8(X2, X3);
    if (t + 1 < SQ) {
      const float* xs = p.x + ((size_t)(t + 1) * BB + rbS + row16) * IN_ + n16 * 16;
      X0 = *(const f32x4*)(xs);
      X1 = *(const f32x4*)(xs + 4);
      X2 = *(const f32x4*)(xs + 8);
      X3 = *(const f32x4*)(xs + 12);
    }
  }

  // ---- B) obtain h_{t-1} into Hs[S] (bf16, swizzled) — tagged LLC ring ----
  char* hrow = HsB + S * 16384 + row16 * 1024;
  if (t == 0) {
    const float* src = p.h0 + (size_t)(rbS + row16) * HH + n16 * 4;
#pragma unroll
    for (int cc = 0; cc < 8; ++cc) {
      f32x4 v = *(const f32x4*)(src + cc * 64);
      unsigned lo = f2b(v.x) | (f2b(v.y) << 16);
      unsigned hi = f2b(v.z) | (f2b(v.w) << 16);
      int boff = ((cc * 128 + n16 * 8) ^ wswz);
      *(uint2*)(hrow + boff) = make_uint2(lo, hi);
    }
  } else if (p.mode == 0) {
    const unsigned* hb = ring + (((t - 1) & 1) ? RINGHALF : 0)
                       + (size_t)(rbS + row16) * HH + n16 * 4;
    u32x4 c0, c1, c2, c3, c4, c5, c6, c7;
    const unsigned tg = (unsigned)t;
#define TAGOK(v) (((v).x >> 16) == tg && ((v).y >> 16) == tg && \
                  ((v).z >> 16) == tg && ((v).w >> 16) == tg)
    int spin = 0;
    for (;;) {
      LOAD8_LLC(c0, c1, c2, c3, c4, c5, c6, c7, hb);
      if (TAGOK(c0) && TAGOK(c1) && TAGOK(c2) && TAGOK(c3) &&
          TAGOK(c4) && TAGOK(c5) && TAGOK(c6) && TAGOK(c7)) break;
      if (++spin > (1 << 16)) break;   // bounded: fail loud, never hang
      if (spin > 8) __builtin_amdgcn_s_sleep(1);
    }
#undef TAGOK
    u32x4 cv[8] = {c0, c1, c2, c3, c4, c5, c6, c7};
#pragma unroll
    for (int cc = 0; cc < 8; ++cc) {
      uint2 u = make_uint2(mergelo(cv[cc].x, cv[cc].y),
                           mergelo(cv[cc].z, cv[cc].w));
      int boff = ((cc * 128 + n16 * 8) ^ wswz);
      *(uint2*)(hrow + boff) = u;
    }
  } else {
    // gridsync fallback: f32 h from d_out via LLC
    cg::this_grid().sync();
    const float* hp = p.out + ((size_t)(t - 1) * BB + rbS + row16) * HH + n16 * 4;
    u32x4 a0, a1, a2, a3, a4, a5, a6, a7;
    LOAD8_LLC(a0, a1, a2, a3, a4, a5, a6, a7, hp);
    u32x4 av[8] = {a0, a1, a2, a3, a4, a5, a6, a7};
#pragma unroll
    for (int cc = 0; cc < 8; ++cc) {
      unsigned lo = f2b(__uint_as_float(av[cc].x)) | (f2b(__uint_as_float(av[cc].y)) << 16);
      unsigned hi = f2b(__uint_as_float(av[cc].z)) | (f2b(__uint_as_float(av[cc].w)) << 16);
      int boff = ((cc * 128 + n16 * 8) ^ wswz);
      *(uint2*)(hrow + boff) = make_uint2(lo, hi);
    }
  }
  __syncthreads();   // barrier 1: Xs[S][t&1] + Hs[S] ready

  // ---- D) 24 MFMAs: 8 from Xs, 16 from Hs — 4 accumulator chains ----
  f32x4 acc0 = { bias, bias, bias, bias };
  f32x4 acc1 = { 0.f, 0.f, 0.f, 0.f };
  f32x4 acc2 = { 0.f, 0.f, 0.f, 0.f };
  f32x4 acc3 = { 0.f, 0.f, 0.f, 0.f };
  const char* xr = XsB + S * 16384 + (t & 1) * 8192 + l16 * 512;
  const char* hr = HsB + S * 16384 + l16 * 1024;
#pragma unroll
  for (int kp = 0; kp < 8; kp += 4) {
    s16x8 a0 = *(const s16x8*)(xr + (((kp + 0) * 64 + lk * 16) ^ rswz));
    s16x8 a1 = *(const s16x8*)(xr + (((kp + 1) * 64 + lk * 16) ^ rswz));
    s16x8 a2 = *(const s16x8*)(xr + (((kp + 2) * 64 + lk * 16) ^ rswz));
    s16x8 a3 = *(const s16x8*)(xr + (((kp + 3) * 64 + lk * 16) ^ rswz));
    acc0 = __builtin_amdgcn_mfma_f32_16x16x32_bf16(a0, bfrag[kp],     acc0, 0, 0, 0);
    acc1 = __builtin_amdgcn_mfma_f32_16x16x32_bf16(a1, bfrag[kp + 1], acc1, 0, 0, 0);
    acc2 = __builtin_amdgcn_mfma_f32_16x16x32_bf16(a2, bfrag[kp + 2], acc2, 0, 0, 0);
    acc3 = __builtin_amdgcn_mfma_f32_16x16x32_bf16(a3, bfrag[kp + 3], acc3, 0, 0, 0);
  }
#pragma unroll
  for (int kp = 0; kp < 16; kp += 4) {
    s16x8 a0 = *(const s16x8*)(hr + (((kp + 0) * 64 + lk * 16) ^ rswz));
    s16x8 a1 = *(const s16x8*)(hr + (((kp + 1) * 64 + lk * 16) ^ rswz));
    s16x8 a2 = *(const s16x8*)(hr + (((kp + 2) * 64 + lk * 16) ^ rswz));
    s16x8 a3 = *(const s16x8*)(hr + (((kp + 3) * 64 + lk * 16) ^ rswz));
    acc0 = __builtin_amdgcn_mfma_f32_16x16x32_bf16(a0, bfrag[8 + kp],  acc0, 0, 0, 0);
    acc1 = __builtin_amdgcn_mfma_f32_16x16x32_bf16(a1, bfrag[9 + kp],  acc1, 0, 0, 0);
    acc2 = __builtin_amdgcn_mfma_f32_16x16x32_bf16(a2, bfrag[10 + kp], acc2, 0, 0, 0);
    acc3 = __builtin_amdgcn_mfma_f32_16x16x32_bf16(a3, bfrag[11 + kp], acc3, 0, 0, 0);
  }

  // ---- E) activations -> gbuf (D-frag: row=lk*4+rr, col=l16) ----
#pragma unroll
  for (int rr = 0; rr < 4; ++rr) {
    float v = (acc0[rr] + acc1[rr]) + (acc2[rr] + acc3[rr]);
    v = (w < 3) ? sigm(v) : tanh_(v);
    gb[w * 272 + (lk * 4 + rr) * 17 + l16] = v;
  }
  __syncthreads();   // barrier 2: gbuf ready

  // ---- F) cell update + publish (coalesced) ----
  float f = gb[0 * 272 + row16 * 17 + n16];
  float i = gb[1 * 272 + row16 * 17 + n16];
  float o = gb[2 * 272 + row16 * 17 + n16];
  float g = gb[3 * 272 + row16 * 17 + n16];
  cval = f * cval + i * g;
  float h = o * tanh_(cval);

  size_t oidx = ((size_t)t * BB + rbS + row16) * HH + hcb + n16;
  if (p.mode == 0) {
    unsigned tw = ((unsigned)(t + 1) << 16) | f2b(h);
    unsigned* dst = ring + ((t & 1) ? RINGHALF : 0)
                  + (size_t)(rbS + row16) * HH + hcb + n16;
    asm volatile("global_store_dword %0, %1, off sc0 sc1"
                 :: "v"(dst), "v"(tw) : "memory");
    __builtin_nontemporal_store(h, p.out + oidx);
  } else {
    asm volatile("global_store_dword %0, %1, off sc0 sc1"
                 :: "v"(p.out + oidx), "v"(h) : "memory");
    asm volatile("s_waitcnt vmcnt(0)" ::: "memory");
  }
  if (t == SQ - 1) {
    size_t base = (size_t)SQ * BB * HH;
    size_t idx2 = (size_t)(rbS + row16) * HH + hcb + n16;
    p.out[base + idx2] = h;
    p.out[base + (size_t)BB * HH + idx2] = cval;
  }
}

__global__ void __launch_bounds__(256, 1) lstm_all(P p) {
  __shared__ unsigned short Hs[2][16][512];      // per-stream h tile, XOR swz
  __shared__ unsigned short Xs[2][2][16][256];   // per-stream x dbuf, XOR swz
  __shared__ float gbuf[4][16][17];              // shared, barrier-guarded

  const int tid = threadIdx.x;
  const int bid = blockIdx.x;
  const int pr  = bid & 3;          // row-pair 0..3
  const int cgi = bid >> 2;         // colgroup 0..31
  const int rbA = pr * 32;          // stream A rows [rbA, rbA+16)
  const int rbB = pr * 32 + 16;     // stream B rows [rbB, rbB+16)
  const int hcb = cgi * 16;

  const int w   = tid >> 6;         // wave = gate (0=f,1=i,2=o,3=g)
  const int l   = tid & 63;
  const int l16 = l & 15;
  const int lk  = l >> 4;
  const int row16 = tid >> 4;       // staging/update row 0..15
  const int n16   = tid & 15;

  unsigned* ring = p.ring;          // valid only in mode 0

  // ---- per-wave B fragments (W|U) -> registers, once; SHARED by streams ----
  const int col = hcb + l16;
  s16x8 bfrag[24];
#pragma unroll
  for (int kk = 0; kk < 24; ++kk) {
    int k = kk * 32 + lk * 8;
    const float* src = (kk < 8) ? (p.W[w] + (size_t)col * IN_ + k)
                                : (p.U[w] + (size_t)col * HH + (k - IN_));
    f32x4 a = *(const f32x4*)src;
    f32x4 b = *(const f32x4*)(src + 4);
    s16x8 v;
    v[0]=(short)f2b(a.x); v[1]=(short)f2b(a.y); v[2]=(short)f2b(a.z); v[3]=(short)f2b(a.w);
    v[4]=(short)f2b(b.x); v[5]=(short)f2b(b.y); v[6]=(short)f2b(b.z); v[7]=(short)f2b(b.w);
    bfrag[kk] = v;
  }
  const float bias = p.bW[w][col] + p.bU[w][col];
  float cvalA = p.c0[(size_t)(rbA + row16) * HH + hcb + n16];
  float cvalB = p.c0[(size_t)(rbB + row16) * HH + hcb + n16];

  const int wswz = (row16 & 7) << 4;   // staging-row byte-XOR key
  const int rswz = (l16 & 7) << 4;     // mfma-read byte-XOR key
  char* HsB = (char*)&Hs[0][0][0];
  char* XsB = (char*)&Xs[0][0][0][0];
  float* gb = &gbuf[0][0][0];

  // ---- prologue: x(t=0) for both streams into registers ----
  f32x4 xA0, xA1, xA2, xA3, xB0, xB1, xB2, xB3;
  {
    const float* xa = p.x + (size_t)(rbA + row16) * IN_ + n16 * 16;
    xA0 = *(const f32x4*)(xa);
    xA1 = *(const f32x4*)(xa + 4);
    xA2 = *(const f32x4*)(xa + 8);
    xA3 = *(const f32x4*)(xa + 12);
    const float* xb = p.x + (size_t)(rbB + row16) * IN_ + n16 * 16;
    xB0 = *(const f32x4*)(xb);
    xB1 = *(const f32x4*)(xb + 4);
    xB2 = *(const f32x4*)(xb + 8);
    xB3 = *(const f32x4*)(xb + 12);
  }

  for (int t = 0; t < SQ; ++t) {
    slot<0>(p, ring, t, rbA, cvalA, xA0, xA1, xA2, xA3,
            HsB, XsB, gb, row16, n16, l16, lk, w, hcb, wswz, rswz, bfrag, bias);
    slot<1>(p, ring, t, rbB, cvalB, xB0, xB1, xB2, xB3,
            HsB, XsB, gb, row16, n16, l16, lk, w, hcb, wswz, rswz, bfrag, bias);
  }
  // LDS reuse safety: Hs/Xs are per-stream (disjoint); gbuf(slot s) writes
  // occur after slot s's barrier 1, by which time all F-phase reads of the
  // previous slot's gbuf have completed (barrier release condition).
  // Ring WAR per stream: identical 2-deep argument to round 8 (a block
  // publishes step t only after consuming tag-t data, which requires every
  // block to have finished its step-(t-1) read of the buffer being written).
}

extern "C" void kernel_launch(void* const* d_in, const int* in_sizes, int n_in,
                              void* d_out, int out_size, void* d_ws, size_t ws_size,
                              hipStream_t stream) {
  P p;
  p.x  = (const float*)d_in[0];
  p.h0 = (const float*)d_in[1];
  p.c0 = (const float*)d_in[2];
  for (int g = 0; g < 4; ++g) {
    p.W[g]  = (const float*)d_in[3 + 4 * g];
    p.bW[g] = (const float*)d_in[4 + 4 * g];
    p.U[g]  = (const float*)d_in[5 + 4 * g];
    p.bU[g] = (const float*)d_in[6 + 4 * g];
  }
  p.out = (float*)d_out;

  const size_t need = (size_t)(RING_OFF + 2 * BB * HH) * sizeof(unsigned);
  const bool ws_ok = (d_ws != nullptr) && (ws_size >= need);
  p.mode = ws_ok ? 0 : 2;
  p.ring = ws_ok ? ((unsigned*)d_ws + RING_OFF) : nullptr;
  if (ws_ok) hipMemsetAsync(d_ws, 0, need, stream);   // tags=0: never valid

  void* args[] = { &p };
  hipError_t e = hipLaunchCooperativeKernel((const void*)lstm_all,
                                            dim3(4 * CGN), dim3(256),
                                            args, 0, stream);
  if (e != hipSuccess) {
    // plain launch: 128 blocks at 1/CU are co-resident; ring protocol valid
    hipLaunchKernelGGL(lstm_all, dim3(4 * CGN), dim3(256), 0, stream, p);
  }
}

// Round 17
// 1291.023 us; speedup vs baseline: 1.9178x; 1.9178x over previous
//
#include <hip/hip_runtime.h>
#include <hip/hip_cooperative_groups.h>

namespace cg = cooperative_groups;

// LSTM S=512,B=128,IN=256,H=512 — persistent kernel, 256 blocks =
// 8 rowgroups(16 batch rows) x 32 colgroups(16 hidden cols; 4 gate-waves).
// Round 17 = ROUND 14 REVERT (proven 1291us, passed incl. re-validation):
// always-LLC tagged bf16 ring (tag travels with data, 1 speculative RT,
// self-healing), coalesced per-thread loads/stores, gbuf gate exchange,
// 2 barriers/step, 4 MFMA accumulator chains, v_perm repack.
// L2-local (sc0-only) mode permanently removed: three failures (R4 slow,
// R7 re-validation fail, R16 timeout) — sc0-scope stores are not promptly
// visible to other CUs; system scope (sc0 sc1) is required and pins RT at
// LLC latency. Step = compute(~1.1us) + LLC visibility(~1.4us); all eight
// structural variants tested regressed — this is the operative optimum.

#define SQ   512
#define BB   128
#define IN_  256
#define HH   512
#define RG   8
#define CGN  32
#define RINGHALF (BB * HH)     // dwords
#define RING_OFF 1024          // dwords (4 KB head, unused)

typedef float    f32x4 __attribute__((ext_vector_type(4)));
typedef short    s16x8 __attribute__((ext_vector_type(8)));
typedef unsigned u32x4 __attribute__((ext_vector_type(4)));

struct P {
  const float *x, *h0, *c0;
  const float *W[4], *bW[4], *U[4], *bU[4];   // gate order f,i,o,g
  float* out;        // [SQ][BB][HH] h_seq, then [BB][HH] h, then [BB][HH] c
  unsigned* ring;    // [2][BB][HH] tagged bf16 h (lo16=payload, hi16=tag)
  int mode;          // 0 = ring protocol, 2 = gridsync fallback (no ws)
};

__device__ __forceinline__ unsigned f2b(float f) {
  unsigned u = __float_as_uint(f);
  return (u + 0x7FFFu + ((u >> 16) & 1u)) >> 16;   // RNE f32->bf16
}
__device__ __forceinline__ float sigm(float x) { return 1.f / (1.f + __expf(-x)); }
__device__ __forceinline__ float tanh_(float x) {
  float e = __expf(-2.f * fabsf(x));
  float t = (1.f - e) / (1.f + e);
  return copysignf(t, x);
}
__device__ __forceinline__ u32x4 pack8(f32x4 a, f32x4 b) {
  u32x4 d;
  d.x = f2b(a.x) | (f2b(a.y) << 16);
  d.y = f2b(a.z) | (f2b(a.w) << 16);
  d.z = f2b(b.x) | (f2b(b.y) << 16);
  d.w = f2b(b.z) | (f2b(b.w) << 16);
  return d;
}
// (d0.lo16) | (d1.lo16 << 16) in one v_perm
__device__ __forceinline__ unsigned mergelo(unsigned d0, unsigned d1) {
  return __builtin_amdgcn_perm(d1, d0, 0x05040100u);
}

// 8x dwordx4 from base+{0,256,...,1792}B, ONE waitcnt, LLC-coherent.
#define LOAD8_LLC(c0_,c1_,c2_,c3_,c4_,c5_,c6_,c7_,ptr_)                      \
  asm volatile(                                                              \
    "global_load_dwordx4 %0, %8, off sc0 sc1\n\t"                            \
    "global_load_dwordx4 %1, %8, off offset:256 sc0 sc1\n\t"                 \
    "global_load_dwordx4 %2, %8, off offset:512 sc0 sc1\n\t"                 \
    "global_load_dwordx4 %3, %8, off offset:768 sc0 sc1\n\t"                 \
    "global_load_dwordx4 %4, %8, off offset:1024 sc0 sc1\n\t"                \
    "global_load_dwordx4 %5, %8, off offset:1280 sc0 sc1\n\t"                \
    "global_load_dwordx4 %6, %8, off offset:1536 sc0 sc1\n\t"                \
    "global_load_dwordx4 %7, %8, off offset:1792 sc0 sc1\n\t"                \
    "s_waitcnt vmcnt(0)"                                                     \
    : "=&v"(c0_), "=&v"(c1_), "=&v"(c2_), "=&v"(c3_),                        \
      "=&v"(c4_), "=&v"(c5_), "=&v"(c6_), "=&v"(c7_)                         \
    : "v"(ptr_) : "memory")

__global__ void __launch_bounds__(256, 1) lstm_all(P p) {
  __shared__ unsigned short Hs[16][512];      // h bf16, rows 1024B, XOR swz
  __shared__ unsigned short Xs[2][16][256];   // x bf16 dbuf, rows 512B, XOR swz
  __shared__ float gbuf[4][16][17];

  const int tid = threadIdx.x;
  const int bid = blockIdx.x;
  const int r   = bid & 7;          // rowgroup
  const int cgi = bid >> 3;         // colgroup
  const int rb  = r * 16;
  const int hcb = cgi * 16;

  const int w   = tid >> 6;         // wave = gate (0=f,1=i,2=o,3=g)
  const int l   = tid & 63;
  const int l16 = l & 15;
  const int lk  = l >> 4;
  const int row16 = tid >> 4;       // staging/update row 0..15
  const int n16   = tid & 15;

  unsigned* ring = p.ring;          // valid only in mode 0

  // ---- per-wave B fragments (W|U) -> registers, bf16, once ----
  const int col = hcb + l16;
  s16x8 bfrag[24];
#pragma unroll
  for (int kk = 0; kk < 24; ++kk) {
    int k = kk * 32 + lk * 8;
    const float* src = (kk < 8) ? (p.W[w] + (size_t)col * IN_ + k)
                                : (p.U[w] + (size_t)col * HH + (k - IN_));
    f32x4 a = *(const f32x4*)src;
    f32x4 b = *(const f32x4*)(src + 4);
    s16x8 v;
    v[0]=(short)f2b(a.x); v[1]=(short)f2b(a.y); v[2]=(short)f2b(a.z); v[3]=(short)f2b(a.w);
    v[4]=(short)f2b(b.x); v[5]=(short)f2b(b.y); v[6]=(short)f2b(b.z); v[7]=(short)f2b(b.w);
    bfrag[kk] = v;
  }
  const float bias = p.bW[w][col] + p.bU[w][col];
  float cval = p.c0[(size_t)(rb + row16) * HH + hcb + n16];

  const int wswz = (row16 & 7) << 4;   // staging-row byte-XOR key
  const int rswz = (l16 & 7) << 4;     // mfma-read byte-XOR key
  char* HsB = (char*)&Hs[0][0];
  char* XsB = (char*)&Xs[0][0][0];

  // ---- prologue: x(t=0) into registers ----
  f32x4 xg0, xg1, xg2, xg3;
  {
    const float* xs = p.x + (size_t)(rb + row16) * IN_ + n16 * 16;
    xg0 = *(const f32x4*)(xs);
    xg1 = *(const f32x4*)(xs + 4);
    xg2 = *(const f32x4*)(xs + 8);
    xg3 = *(const f32x4*)(xs + 12);
  }

  for (int t = 0; t < SQ; ++t) {
    // ---- A) Xs[t&1] <- xreg; issue x(t+1) loads (hide under ring read) ----
    {
      char* xrow = XsB + (t & 1) * 8192 + row16 * 512;
      *(u32x4*)(xrow + ((n16 * 32)      ^ wswz)) = pack8(xg0, xg1);
      *(u32x4*)(xrow + ((n16 * 32 + 16) ^ wswz)) = pack8(xg2, xg3);
      if (t + 1 < SQ) {
        const float* xs = p.x + ((size_t)(t + 1) * BB + rb + row16) * IN_ + n16 * 16;
        xg0 = *(const f32x4*)(xs);
        xg1 = *(const f32x4*)(xs + 4);
        xg2 = *(const f32x4*)(xs + 8);
        xg3 = *(const f32x4*)(xs + 12);
      }
    }

    // ---- B) obtain h_{t-1} into Hs (bf16, swizzled) — tagged LLC ring ----
    char* hrow = HsB + row16 * 1024;
    if (t == 0) {
      const float* src = p.h0 + (size_t)(rb + row16) * HH + n16 * 4;
#pragma unroll
      for (int cc = 0; cc < 8; ++cc) {
        f32x4 v = *(const f32x4*)(src + cc * 64);
        unsigned lo = f2b(v.x) | (f2b(v.y) << 16);
        unsigned hi = f2b(v.z) | (f2b(v.w) << 16);
        int boff = ((cc * 128 + n16 * 8) ^ wswz);
        *(uint2*)(hrow + boff) = make_uint2(lo, hi);
      }
    } else if (p.mode == 0) {
      const unsigned* hb = ring + (((t - 1) & 1) ? RINGHALF : 0)
                         + (size_t)(rb + row16) * HH + n16 * 4;
      u32x4 c0,c1,c2,c3,c4,c5,c6,c7;
      const unsigned tg = (unsigned)t;
#define TAGOK(v) (((v).x >> 16) == tg && ((v).y >> 16) == tg && \
                  ((v).z >> 16) == tg && ((v).w >> 16) == tg)
      int spin = 0;
      for (;;) {
        LOAD8_LLC(c0,c1,c2,c3,c4,c5,c6,c7,hb);
        if (TAGOK(c0) && TAGOK(c1) && TAGOK(c2) && TAGOK(c3) &&
            TAGOK(c4) && TAGOK(c5) && TAGOK(c6) && TAGOK(c7)) break;
        if (++spin > (1 << 16)) break;   // bounded: fail loud, never hang
        if (spin > 8) __builtin_amdgcn_s_sleep(1);
      }
#undef TAGOK
      u32x4 cv[8] = {c0,c1,c2,c3,c4,c5,c6,c7};
#pragma unroll
      for (int cc = 0; cc < 8; ++cc) {
        uint2 u = make_uint2(mergelo(cv[cc].x, cv[cc].y),
                             mergelo(cv[cc].z, cv[cc].w));
        int boff = ((cc * 128 + n16 * 8) ^ wswz);
        *(uint2*)(hrow + boff) = u;
      }
    } else {
      // gridsync fallback: f32 h from d_out via LLC
      cg::this_grid().sync();
      const float* hp = p.out + ((size_t)(t - 1) * BB + rb + row16) * HH + n16 * 4;
      u32x4 a0,a1,a2,a3,a4,a5,a6,a7;
      LOAD8_LLC(a0,a1,a2,a3,a4,a5,a6,a7,hp);
      u32x4 av[8] = {a0,a1,a2,a3,a4,a5,a6,a7};
#pragma unroll
      for (int cc = 0; cc < 8; ++cc) {
        unsigned lo = f2b(__uint_as_float(av[cc].x)) | (f2b(__uint_as_float(av[cc].y)) << 16);
        unsigned hi = f2b(__uint_as_float(av[cc].z)) | (f2b(__uint_as_float(av[cc].w)) << 16);
        int boff = ((cc * 128 + n16 * 8) ^ wswz);
        *(uint2*)(hrow + boff) = make_uint2(lo, hi);
      }
    }
    __syncthreads();   // barrier 1: Xs[t&1] + Hs ready

    // ---- D) 24 MFMAs: 8 from Xs, 16 from Hs — FOUR accumulator chains ----
    f32x4 acc0 = { bias, bias, bias, bias };
    f32x4 acc1 = { 0.f, 0.f, 0.f, 0.f };
    f32x4 acc2 = { 0.f, 0.f, 0.f, 0.f };
    f32x4 acc3 = { 0.f, 0.f, 0.f, 0.f };
    const char* xr = XsB + (t & 1) * 8192 + l16 * 512;
    const char* hr = HsB + l16 * 1024;
#pragma unroll
    for (int kp = 0; kp < 8; kp += 4) {
      s16x8 a0 = *(const s16x8*)(xr + (((kp + 0) * 64 + lk * 16) ^ rswz));
      s16x8 a1 = *(const s16x8*)(xr + (((kp + 1) * 64 + lk * 16) ^ rswz));
      s16x8 a2 = *(const s16x8*)(xr + (((kp + 2) * 64 + lk * 16) ^ rswz));
      s16x8 a3 = *(const s16x8*)(xr + (((kp + 3) * 64 + lk * 16) ^ rswz));
      acc0 = __builtin_amdgcn_mfma_f32_16x16x32_bf16(a0, bfrag[kp],     acc0, 0, 0, 0);
      acc1 = __builtin_amdgcn_mfma_f32_16x16x32_bf16(a1, bfrag[kp + 1], acc1, 0, 0, 0);
      acc2 = __builtin_amdgcn_mfma_f32_16x16x32_bf16(a2, bfrag[kp + 2], acc2, 0, 0, 0);
      acc3 = __builtin_amdgcn_mfma_f32_16x16x32_bf16(a3, bfrag[kp + 3], acc3, 0, 0, 0);
    }
#pragma unroll
    for (int kp = 0; kp < 16; kp += 4) {
      s16x8 a0 = *(const s16x8*)(hr + (((kp + 0) * 64 + lk * 16) ^ rswz));
      s16x8 a1 = *(const s16x8*)(hr + (((kp + 1) * 64 + lk * 16) ^ rswz));
      s16x8 a2 = *(const s16x8*)(hr + (((kp + 2) * 64 + lk * 16) ^ rswz));
      s16x8 a3 = *(const s16x8*)(hr + (((kp + 3) * 64 + lk * 16) ^ rswz));
      acc0 = __builtin_amdgcn_mfma_f32_16x16x32_bf16(a0, bfrag[8 + kp],  acc0, 0, 0, 0);
      acc1 = __builtin_amdgcn_mfma_f32_16x16x32_bf16(a1, bfrag[9 + kp],  acc1, 0, 0, 0);
      acc2 = __builtin_amdgcn_mfma_f32_16x16x32_bf16(a2, bfrag[10 + kp], acc2, 0, 0, 0);
      acc3 = __builtin_amdgcn_mfma_f32_16x16x32_bf16(a3, bfrag[11 + kp], acc3, 0, 0, 0);
    }

    // ---- E) activations -> gbuf (D-frag: row=lk*4+rr, col=l16) ----
#pragma unroll
    for (int rr = 0; rr < 4; ++rr) {
      float v = (acc0[rr] + acc1[rr]) + (acc2[rr] + acc3[rr]);
      v = (w < 3) ? sigm(v) : tanh_(v);
      gbuf[w][lk * 4 + rr][l16] = v;
    }
    __syncthreads();   // barrier 2: gbuf ready

    // ---- F) cell update + publish (coalesced) ----
    float f = gbuf[0][row16][n16];
    float i = gbuf[1][row16][n16];
    float o = gbuf[2][row16][n16];
    float g = gbuf[3][row16][n16];
    cval = f * cval + i * g;
    float h = o * tanh_(cval);

    size_t oidx = ((size_t)t * BB + rb + row16) * HH + hcb + n16;
    if (p.mode == 0) {
      unsigned tw = ((unsigned)(t + 1) << 16) | f2b(h);
      unsigned* dst = ring + ((t & 1) ? RINGHALF : 0)
                    + (size_t)(rb + row16) * HH + hcb + n16;
      asm volatile("global_store_dword %0, %1, off sc0 sc1"
                   :: "v"(dst), "v"(tw) : "memory");
      __builtin_nontemporal_store(h, p.out + oidx);
    } else {
      asm volatile("global_store_dword %0, %1, off sc0 sc1"
                   :: "v"(p.out + oidx), "v"(h) : "memory");
      asm volatile("s_waitcnt vmcnt(0)" ::: "memory");
    }
    if (t == SQ - 1) {
      size_t base = (size_t)SQ * BB * HH;
      size_t idx2 = (size_t)(rb + row16) * HH + hcb + n16;
      p.out[base + idx2] = h;
      p.out[base + (size_t)BB * HH + idx2] = cval;
    }
    // next iteration's post-B __syncthreads covers Hs/gbuf/Xs reuse
  }
}

extern "C" void kernel_launch(void* const* d_in, const int* in_sizes, int n_in,
                              void* d_out, int out_size, void* d_ws, size_t ws_size,
                              hipStream_t stream) {
  P p;
  p.x  = (const float*)d_in[0];
  p.h0 = (const float*)d_in[1];
  p.c0 = (const float*)d_in[2];
  for (int g = 0; g < 4; ++g) {
    p.W[g]  = (const float*)d_in[3 + 4 * g];
    p.bW[g] = (const float*)d_in[4 + 4 * g];
    p.U[g]  = (const float*)d_in[5 + 4 * g];
    p.bU[g] = (const float*)d_in[6 + 4 * g];
  }
  p.out = (float*)d_out;

  const size_t need = (size_t)(RING_OFF + 2 * BB * HH) * sizeof(unsigned);
  const bool ws_ok = (d_ws != nullptr) && (ws_size >= need);
  p.mode = ws_ok ? 0 : 2;
  p.ring = ws_ok ? ((unsigned*)d_ws + RING_OFF) : nullptr;
  if (ws_ok) hipMemsetAsync(d_ws, 0, need, stream);   // tags=0: never valid

  void* args[] = { &p };
  hipError_t e = hipLaunchCooperativeKernel((const void*)lstm_all,
                                            dim3(RG * CGN), dim3(256),
                                            args, 0, stream);
  if (e != hipSuccess) {
    // plain launch: 256 blocks at 1/CU are co-resident; ring protocol valid
    hipLaunchKernelGGL(lstm_all, dim3(RG * CGN), dim3(256), 0, stream, p);
  }
}